// Round 1
// 81.422 us; speedup vs baseline: 1.0641x; 1.0641x over previous
//
#include <hip/hip_runtime.h>
#include <math.h>

#define SRATE 16000
#define FRAME 320
#define LAGS 189
#define LAG_MIN 5
#define WIN_MED 30
#define BATCH 8
#define TLEN 80000
#define KFRAMES 250           // ceil(80000/320)
#define NOUT 235              // 250 + 14 - 30 + 1
#define NTOT (BATCH * NOUT)   // 1880
#define SEG (FRAME + LAGS)    // 509

// ---------------- Kernel 1: NCCF + best lag + frame energy ----------------
// R4: one 256-thread block (4 waves) per frame. The 320-sample K dimension is
// split across the 4 waves (80 samples each) -> per-wave serial loop drops
// 80 -> 20 iterations and the machine holds 8000 waves (~31/CU) instead of
// 2000 (~8/CU), hiding the ds_read->FMA latency chain. Partial cr/e2/e1 are
// reduced through LDS; the argmax is wave-parallel (shuffle butterfly) with
// first-max tie-breaking instead of a serial 184-step lane-0 loop.
__global__ __launch_bounds__(256) void nccf_best_kernel(
    const float* __restrict__ audio, int* __restrict__ best,
    float* __restrict__ out) {
  const int k = blockIdx.x;
  const int b = blockIdx.y;
  const float* row = audio + (size_t)b * TLEN;
  const int base = k * FRAME;

  __shared__ float sh[512];        // seg[0..508], zero-padded to 512
  __shared__ float pcr[4][192];    // per-wave partial cross
  __shared__ float pe2[4][192];    // per-wave partial energy2
  __shared__ float pe1[4];         // per-wave partial energy1
  __shared__ float shv[192];       // nccf values per lag

  const int tid = threadIdx.x;

  // stage 512 floats (values beyond SEG or TLEN are zero)
  if (tid < 128) {
    int j = 4 * tid;
    float4 v;
    if (j + 3 < SEG && base + j + 3 < TLEN) {
      v = *(const float4*)(row + base + j);
    } else {
      v.x = (j + 0 < SEG && base + j + 0 < TLEN) ? row[base + j + 0] : 0.0f;
      v.y = (j + 1 < SEG && base + j + 1 < TLEN) ? row[base + j + 1] : 0.0f;
      v.z = (j + 2 < SEG && base + j + 2 < TLEN) ? row[base + j + 2] : 0.0f;
      v.w = (j + 3 < SEG && base + j + 3 < TLEN) ? row[base + j + 3] : 0.0f;
    }
    *(float4*)&sh[j] = v;
  }
  __syncthreads();

  const int w = tid >> 6;          // wave id: owns samples [80w, 80w+80)
  const int lane = tid & 63;

  if (lane < 48) {
    const int i0b = w * 80;
    float wv[8];
    *(float4*)&wv[0] = *(const float4*)&sh[4 * lane + i0b];
    float cr[4] = {0.f, 0.f, 0.f, 0.f};
    float e2[4] = {0.f, 0.f, 0.f, 0.f};
    float e1 = 0.f;
    for (int ii = 0; ii < 80; ii += 4) {
      float4 a = *(const float4*)&sh[i0b + ii];                // broadcast
      *(float4*)&wv[4] = *(const float4*)&sh[4 * lane + i0b + ii + 4];
      e1 += a.x * a.x + a.y * a.y + a.z * a.z + a.w * a.w;
      #pragma unroll
      for (int d = 0; d < 4; ++d) {
        float c0 = wv[d + 1], c1 = wv[d + 2], c2 = wv[d + 3], c3 = wv[d + 4];
        cr[d] += a.x * c0 + a.y * c1 + a.z * c2 + a.w * c3;
        e2[d] += c0 * c0 + c1 * c1 + c2 * c2 + c3 * c3;
      }
      wv[0] = wv[4]; wv[1] = wv[5]; wv[2] = wv[6]; wv[3] = wv[7];
    }
    *(float4*)&pcr[w][4 * lane] = *(float4*)cr;
    *(float4*)&pe2[w][4 * lane] = *(float4*)e2;
    if (lane == 0) pe1[w] = e1;
  }
  __syncthreads();

  // combine partials: one thread per lag (fixed summation order w=0..3)
  if (tid < LAGS) {
    float crs = pcr[0][tid] + pcr[1][tid] + pcr[2][tid] + pcr[3][tid];
    float e2s = pe2[0][tid] + pe2[1][tid] + pe2[2][tid] + pe2[3][tid];
    float e1s = pe1[0] + pe1[1] + pe1[2] + pe1[3];
    float d1 = 1e-9f + sqrtf(e1s);
    float d2 = 1e-9f + sqrtf(e2s);
    shv[tid] = crs / (d1 * d1) / (d2 * d2);
    if (tid == 0) out[3 * NTOT + b * KFRAMES + k] = e1s * (1.0f / FRAME);
  }
  __syncthreads();

  // wave 0: parallel argmax over [LAG_MIN, LAGS) and half range [LAG_MIN, 94)
  // first-max semantics preserved: prefer smaller index on exact value ties.
  if (w == 0) {
    float bv = -INFINITY; int bi = 0;
    float hv = -INFINITY; int hi2 = 0;
    #pragma unroll
    for (int r = 0; r < 3; ++r) {
      int ll = LAG_MIN + lane + 64 * r;
      if (ll < LAGS) {
        float v = shv[ll];
        if (v > bv || (v == bv && ll < bi)) { bv = v; bi = ll; }
        if (ll < (LAGS / 2) && (v > hv || (v == hv && ll < hi2))) { hv = v; hi2 = ll; }
      }
    }
    #pragma unroll
    for (int off = 32; off >= 1; off >>= 1) {
      float ov = __shfl_xor(bv, off, 64);
      int   oi = __shfl_xor(bi, off, 64);
      if (ov > bv || (ov == bv && oi < bi)) { bv = ov; bi = oi; }
      float ohv = __shfl_xor(hv, off, 64);
      int   ohi = __shfl_xor(hi2, off, 64);
      if (ohv > hv || (ohv == hv && ohi < hi2)) { hv = ohv; hi2 = ohi; }
    }
    if (lane == 0) {
      int chosen = (hv > 0.99f * bv) ? hi2 : bi;
      best[b * KFRAMES + k] = chosen + 1;
    }
  }
}

// ---------------- Kernel 2: median smoothing (one wave per output) ----------------
// Rank-14 select via shuffle broadcasts: no private arrays -> no scratch spill.
__global__ __launch_bounds__(256) void median_f0_kernel(
    const int* __restrict__ best, float* __restrict__ out) {
  const int w = blockIdx.x * 4 + (threadIdx.x >> 6);   // wave id = output id
  const int lane = threadIdx.x & 63;
  const int b = w / NOUT;
  const int t = w - b * NOUT;

  int v = 0x7fffffff;
  if (lane < WIN_MED) {
    int j = t + lane - 14;               // left replicate-pad by 14
    if (j < 0) j = 0;
    v = best[b * KFRAMES + j];
  }
  int c_lt = 0, c_le = 0;
  #pragma unroll
  for (int j = 0; j < WIN_MED; ++j) {
    int bv = __shfl(v, j, 64);
    c_lt += (bv < v) ? 1 : 0;
    c_le += (bv <= v) ? 1 : 0;
  }
  // lower median = sorted[14]: value with count(<v) <= 14 < count(<=v)
  bool cond = (lane < WIN_MED) && (c_lt <= 14) && (c_le > 14);
  unsigned long long m = __ballot(cond);
  int sel = __ffsll((long long)m) - 1;
  int med = __shfl(v, sel, 64);
  if (lane == 0) {
    float f0 = 16000.0f / (1e-9f + (float)med);
    out[b * NOUT + t] = f0;              // f0
    out[2 * NTOT + b * NOUT + t] = 1.0f; // voiced (f0 > 0 always)
  }
}

// ---------------- Kernel 3: whiten (single block: reduce + apply) ----------------
__global__ __launch_bounds__(256) void whiten_kernel(float* __restrict__ out) {
  __shared__ double red[256];
  __shared__ double red2[256];
  const int t = threadIdx.x;
  double s = 0.0, s2 = 0.0;
  for (int i = t; i < NTOT; i += 256) {
    double f = (double)out[i];
    s += f; s2 += f * f;
  }
  red[t] = s; red2[t] = s2;
  __syncthreads();
  for (int st = 128; st > 0; st >>= 1) {
    if (t < st) { red[t] += red[t + st]; red2[t] += red2[t + st]; }
    __syncthreads();
  }
  __shared__ float fmean_s, finvsd_s;
  if (t == 0) {
    const double n = (double)NTOT;
    double mean = red[0] / n;
    double var = (red2[0] - n * mean * mean) / (n - 1.0);
    if (var < 0.0) var = 0.0;
    double sd = sqrt(var);
    fmean_s = (float)mean;
    finvsd_s = (sd == 0.0) ? 1.0f : (float)(1.0 / sd);
  }
  __syncthreads();
  float fmean = fmean_s, finvsd = finvsd_s;
  for (int i = t; i < NTOT; i += 256) {
    out[NTOT + i] = (out[i] - fmean) * finvsd;
  }
}

extern "C" void kernel_launch(void* const* d_in, const int* in_sizes, int n_in,
                              void* d_out, int out_size, void* d_ws, size_t ws_size,
                              hipStream_t stream) {
  const float* audio = (const float*)d_in[0];
  float* out = (float*)d_out;
  int* best = (int*)d_ws;   // 2000 ints

  dim3 g1(KFRAMES, BATCH);
  nccf_best_kernel<<<g1, 256, 0, stream>>>(audio, best, out);
  median_f0_kernel<<<(NTOT + 3) / 4, 256, 0, stream>>>(best, out);
  whiten_kernel<<<1, 256, 0, stream>>>(out);
}